// Round 8
// baseline (196.074 us; speedup 1.0000x reference)
//
#include <hip/hip_runtime.h>

#define NODES 10000
#define BATCH 8
#define CH    128
#define KNB   16
#define CO    256

typedef __bf16 bf16x8 __attribute__((ext_vector_type(8)));
typedef float  f32x4  __attribute__((ext_vector_type(4)));

__device__ __forceinline__ unsigned short f2bf(float f) {
  unsigned u = __float_as_uint(f);
  u = (u + 0x7FFFu + ((u >> 16) & 1u)) >> 16;   // RNE
  return (unsigned short)u;
}

// max of packed non-negative bf16 == packed u16 max (relu guarantees >=0)
__device__ __forceinline__ unsigned pkmax(unsigned a, unsigned b) {
  unsigned d;
  asm("v_pk_max_u16 %0, %1, %2" : "=v"(d) : "v"(a), "v"(b));
  return d;
}
__device__ __forceinline__ uint4 pkmax4(uint4 a, uint4 b) {
  a.x = pkmax(a.x, b.x); a.y = pkmax(a.y, b.y);
  a.z = pkmax(a.z, b.z); a.w = pkmax(a.w, b.w);
  return a;
}
__device__ __forceinline__ bf16x8 asbf8(uint4 u) {
  union { uint4 u; bf16x8 b; } c; c.u = u; return c.b;
}

// async global->LDS DMA, 16B per lane; LDS dst = base + lane*16 (linear)
__device__ __forceinline__ void gload_lds16(const void* g, void* l) {
  __builtin_amdgcn_global_load_lds(
      (const __attribute__((address_space(1))) unsigned int*)g,
      (__attribute__((address_space(3))) unsigned int*)l, 16, 0, 0);
}

// LDS-only barrier: waits LDS ops, NOT outstanding global stores / LDS-DMA.
// (DMA'd buffers are guarded separately by counted vmcnt at tile boundaries.)
__device__ __forceinline__ void lds_barrier() {
  asm volatile("s_waitcnt lgkmcnt(0)" ::: "memory");
  __builtin_amdgcn_sched_barrier(0);
  __builtin_amdgcn_s_barrier();
}

// ---------------------------------------------------------------------------
// fp32 -> bf16 weight conversion (row-major [d][k] kept)
// ---------------------------------------------------------------------------
__global__ __launch_bounds__(256) void prep(
    const float* __restrict__ W1, const float* __restrict__ Wp,
    const float* __restrict__ W2,
    unsigned short* __restrict__ W1b, unsigned short* __restrict__ Wpb,
    unsigned short* __restrict__ W2b)
{
  int i = blockIdx.x * 256 + threadIdx.x;   // float4 index, 24576 total
  const float* src; unsigned short* dst; int off;
  if (i < 4096)      { src = W1; dst = W1b; off = i; }
  else if (i < 8192) { src = Wp; dst = Wpb; off = i - 4096; }
  else               { src = W2; dst = W2b; off = i - 8192; }
  float4 v = ((const float4*)src)[off];
  ushort4 o;
  o.x = f2bf(v.x); o.y = f2bf(v.y); o.z = f2bf(v.z); o.w = f2bf(v.w);
  ((ushort4*)dst)[off] = o;
}

// ---------------------------------------------------------------------------
// prep_x: x fp32 [b][c][n] -> x_t bf16 [b][n][128] (node-major). (unchanged)
// ---------------------------------------------------------------------------
__global__ __launch_bounds__(256) void prep_x(
    const float* __restrict__ x, unsigned short* __restrict__ x_t)
{
  const int b  = blockIdx.y;
  const int n0 = blockIdx.x * 64;
  const int t  = threadIdx.x;
  const size_t nb = (size_t)b * NODES;

  __shared__ __align__(16) unsigned short Bt[64 * 128];   // 16 KB
  char* BtB = (char*)Bt;

  const float* X = x + (size_t)b * CH * NODES;
#pragma unroll
  for (int rep = 0; rep < 4; ++rep) {
    int flat = t + rep * 256;
    int c2 = flat >> 4, n4 = flat & 15;
    int c  = c2 * 2;
    int gn = n0 + n4 * 4;
    float4 a0 = make_float4(0.f,0.f,0.f,0.f), a1 = a0;
    if (gn < NODES) {
      a0 = *(const float4*)(X + (size_t)c * NODES + gn);
      a1 = *(const float4*)(X + (size_t)(c + 1) * NODES + gn);
    }
    float v0[4] = {a0.x, a0.y, a0.z, a0.w};
    float v1[4] = {a1.x, a1.y, a1.z, a1.w};
#pragma unroll
    for (int i = 0; i < 4; ++i) {
      int nn = n4 * 4 + i;
      unsigned pk = (unsigned)f2bf(v0[i]) | ((unsigned)f2bf(v1[i]) << 16);
      int phys = nn * 256 + (((c2 >> 2) ^ (nn & 7)) << 4) + ((c2 & 3) << 2);
      *(unsigned*)(BtB + phys) = pk;
    }
  }
  __syncthreads();

  // coalesced writeback: quad per node, logical chunk order
  {
    int nl = t >> 2;
    int gn = n0 + nl;
#pragma unroll
    for (int rep = 0; rep < 4; ++rep) {
      int g = (t & 3) + rep * 4;
      int phys = nl * 256 + ((g ^ (nl & 7)) << 4);
      uint4 v = *(const uint4*)(BtB + phys);
      if (gn < NODES)
        *(uint4*)((char*)x_t + (nb + (size_t)gn) * 256 + g * 16) = v;
    }
  }
}

// ---------------------------------------------------------------------------
// fused_hz v4: v3 pipeline + T4 counted-vmcnt boundaries + LDS-only internal
// barriers. Per wave per tile VMEM order: [4 DMA (oldest, pinned by
// sched_barrier in hz_stage)] ... [bias loads][4 h-stores][4 z-stores].
// Boundary vmcnt(8): 8 stores are ALWAYS newer than the DMAs, so waiting
// "until <=8 outstanding" guarantees the 4 DMAs retired while stores keep
// draining under the next tile's MFMA. Internal barriers are lgkm-only, so
// next-tile DMAs stay in flight across them.
// ---------------------------------------------------------------------------
__device__ __forceinline__ void hz_stage(
    unsigned short* buf, const unsigned short* __restrict__ x_t,
    size_t nb, int n0, int w, int lane)
{
#pragma unroll
  for (int rep = 0; rep < 4; ++rep) {
    const int row0 = w * 16 + rep * 4;          // wave-uniform base row
    const int nl = row0 + (lane >> 4);          // 4 rows per issue
    const int c  = lane & 15;                   // physical chunk
    const int l  = c ^ (nl & 7);                // logical chunk (involution)
    int gn = n0 + nl; if (gn > NODES - 1) gn = NODES - 1;   // clamp, masked later
    const unsigned short* src = x_t + (nb + (size_t)gn) * CH + l * 8;
    gload_lds16(src, (char*)buf + row0 * 256);
  }
  __builtin_amdgcn_sched_barrier(0);   // pin DMA issue before anything later
}

__device__ __forceinline__ void hz_compute(
    const unsigned short* buf, unsigned short* Ht, unsigned short* Zt,
    const uint4 (&af)[4][4], const uint4 (&af2)[4][4],
    const float* __restrict__ b1, const float* __restrict__ bp,
    unsigned short* __restrict__ h_t, unsigned short* __restrict__ z_t,
    size_t nb, int n0, int t, int w, int lm, int q)
{
  const char* BtB = (const char*)buf;
  char* HtB = (char*)Ht;
  char* ZtB = (char*)Zt;
  const int d0  = (w & 1) * 64;
  const int nbw = (w >> 1) * 32;

  // ---- phase 1 MFMA: h-tile
  f32x4 acc[4][2];
#pragma unroll
  for (int dt = 0; dt < 4; ++dt)
#pragma unroll
    for (int nt = 0; nt < 2; ++nt) acc[dt][nt] = (f32x4){0.f,0.f,0.f,0.f};

#pragma unroll
  for (int kt = 0; kt < 4; ++kt)
#pragma unroll
    for (int nt = 0; nt < 2; ++nt) {
      int nl = nbw + nt * 16 + lm;
      int chunk = kt * 4 + q;
      int phys = nl * 256 + ((chunk ^ (nl & 7)) << 4);
      bf16x8 bb = asbf8(*(const uint4*)(BtB + phys));
#pragma unroll
      for (int dt = 0; dt < 4; ++dt)
        acc[dt][nt] = __builtin_amdgcn_mfma_f32_16x16x32_bf16(
            asbf8(af[dt][kt]), bb, acc[dt][nt], 0, 0, 0);
    }

  // ---- epilogue 1: bias+relu+bf16 -> Ht (B-frag layout)
#pragma unroll
  for (int dt = 0; dt < 4; ++dt) {
    int dbase = d0 + dt * 16 + q * 4;
    float4 bi = *(const float4*)(b1 + dbase);
    float bv[4] = {bi.x, bi.y, bi.z, bi.w};
#pragma unroll
    for (int nt = 0; nt < 2; ++nt) {
      int nl = nbw + nt * 16 + lm;
      ushort4 o;
      o.x = f2bf(fmaxf(acc[dt][nt][0] + bv[0], 0.f));
      o.y = f2bf(fmaxf(acc[dt][nt][1] + bv[1], 0.f));
      o.z = f2bf(fmaxf(acc[dt][nt][2] + bv[2], 0.f));
      o.w = f2bf(fmaxf(acc[dt][nt][3] + bv[3], 0.f));
      int chunk = dbase >> 3;
      int phys  = nl * 256 + ((chunk ^ (nl & 7)) << 4) + ((q & 1) << 3);
      *(ushort4*)(HtB + phys) = o;
    }
  }

  lds_barrier();   // Ht complete (LDS-only: stores/DMA stay in flight)

  // ---- coalesced h_t store (fire-and-forget; drains under MFMA2)
  {
    int nl = t >> 2;
    int gn = n0 + nl;
#pragma unroll
    for (int rep = 0; rep < 4; ++rep) {
      int g = (t & 3) + rep * 4;
      int phys = nl * 256 + ((g ^ (nl & 7)) << 4);
      uint4 v = *(const uint4*)(HtB + phys);
      if (gn < NODES)
        *(uint4*)((char*)h_t + (nb + (size_t)gn) * 256 + g * 16) = v;
    }
  }

  // ---- phase 2 MFMA: z-tile from Ht
#pragma unroll
  for (int dt = 0; dt < 4; ++dt)
#pragma unroll
    for (int nt = 0; nt < 2; ++nt) acc[dt][nt] = (f32x4){0.f,0.f,0.f,0.f};

#pragma unroll
  for (int kt = 0; kt < 4; ++kt)
#pragma unroll
    for (int nt = 0; nt < 2; ++nt) {
      int nl = nbw + nt * 16 + lm;
      int chunk = kt * 4 + q;
      int phys = nl * 256 + ((chunk ^ (nl & 7)) << 4);
      bf16x8 bb = asbf8(*(const uint4*)(HtB + phys));
#pragma unroll
      for (int dt = 0; dt < 4; ++dt)
        acc[dt][nt] = __builtin_amdgcn_mfma_f32_16x16x32_bf16(
            asbf8(af2[dt][kt]), bb, acc[dt][nt], 0, 0, 0);
    }

  // ---- epilogue 2: z -> Zt (B-frag layout)
#pragma unroll
  for (int dt = 0; dt < 4; ++dt) {
    int dbase = d0 + dt * 16 + q * 4;
    float4 bi = *(const float4*)(bp + dbase);
    float bv[4] = {bi.x, bi.y, bi.z, bi.w};
#pragma unroll
    for (int nt = 0; nt < 2; ++nt) {
      int nl = nbw + nt * 16 + lm;
      ushort4 o;
      o.x = f2bf(fmaxf(acc[dt][nt][0] + bv[0], 0.f));
      o.y = f2bf(fmaxf(acc[dt][nt][1] + bv[1], 0.f));
      o.z = f2bf(fmaxf(acc[dt][nt][2] + bv[2], 0.f));
      o.w = f2bf(fmaxf(acc[dt][nt][3] + bv[3], 0.f));
      int chunk = dbase >> 3;
      int phys  = nl * 256 + ((chunk ^ (nl & 7)) << 4) + ((q & 1) << 3);
      *(ushort4*)(ZtB + phys) = o;
    }
  }

  lds_barrier();   // Zt complete (LDS-only)

  // ---- coalesced z_t store (fire-and-forget)
  {
    int nl = t >> 2;
    int gn = n0 + nl;
#pragma unroll
    for (int rep = 0; rep < 4; ++rep) {
      int g = (t & 3) + rep * 4;
      int phys = nl * 256 + ((g ^ (nl & 7)) << 4);
      uint4 v = *(const uint4*)(ZtB + phys);
      if (gn < NODES)
        *(uint4*)((char*)z_t + (nb + (size_t)gn) * 256 + g * 16) = v;
    }
  }
}

__global__ __launch_bounds__(256) void fused_hz(
    const unsigned short* __restrict__ W1b, const float* __restrict__ b1,
    const unsigned short* __restrict__ Wpb, const float* __restrict__ bp,
    const unsigned short* __restrict__ x_t,
    unsigned short* __restrict__ h_t, unsigned short* __restrict__ z_t)
{
  const int bid = blockIdx.x;
  const int b   = bid & 7;
  const int g   = bid >> 3;                // 0..63
  const int t   = threadIdx.x;
  const int lane = t & 63, w = t >> 6;
  const int lm = lane & 15, q = lane >> 4;
  const size_t nb = (size_t)b * NODES;

  __shared__ __align__(16) unsigned short bufA[64 * 128];   // 16 KB
  __shared__ __align__(16) unsigned short bufB[64 * 128];   // 16 KB
  __shared__ __align__(16) unsigned short Ht[64 * 128];     // 16 KB
  __shared__ __align__(16) unsigned short Zt[64 * 128];     // 16 KB

  const int d0 = (w & 1) * 64;

  // W1 + Wp A-fragments, tile-invariant (preload once)
  uint4 af[4][4], af2[4][4];
#pragma unroll
  for (int dt = 0; dt < 4; ++dt)
#pragma unroll
    for (int kt = 0; kt < 4; ++kt) {
      af[dt][kt]  = *(const uint4*)(W1b + (d0 + dt*16 + lm) * CH + kt*32 + q*8);
      af2[dt][kt] = *(const uint4*)(Wpb + (d0 + dt*16 + lm) * CH + kt*32 + q*8);
    }

  const int n0_0 = g * 64;
  const int n0_1 = (g + 64) * 64;
  const int n0_2 = (g + 128) * 64;
  const bool has2 = (g + 128) < 157;

  // prologue: stage tile0 (no stores outstanding -> must be vmcnt(0))
  hz_stage(bufA, x_t, nb, n0_0, w, lane);
  asm volatile("s_waitcnt vmcnt(0) lgkmcnt(0)" ::: "memory");
  __builtin_amdgcn_sched_barrier(0);
  __builtin_amdgcn_s_barrier();

  // iter 0: stage t1 (DMAs oldest), compute t0 (8 stores newer)
  hz_stage(bufB, x_t, nb, n0_1, w, lane);
  hz_compute(bufA, Ht, Zt, af, af2, b1, bp, h_t, z_t, nb, n0_0, t, w, lm, q);
  asm volatile("s_waitcnt vmcnt(8) lgkmcnt(0)" ::: "memory");   // release DMAs only
  __builtin_amdgcn_sched_barrier(0);
  __builtin_amdgcn_s_barrier();

  if (has2) {
    hz_stage(bufA, x_t, nb, n0_2, w, lane);
    hz_compute(bufB, Ht, Zt, af, af2, b1, bp, h_t, z_t, nb, n0_1, t, w, lm, q);
    asm volatile("s_waitcnt vmcnt(8) lgkmcnt(0)" ::: "memory");
    __builtin_amdgcn_sched_barrier(0);
    __builtin_amdgcn_s_barrier();
    hz_compute(bufA, Ht, Zt, af, af2, b1, bp, h_t, z_t, nb, n0_2, t, w, lm, q);
  } else {
    hz_compute(bufB, Ht, Zt, af, af2, b1, bp, h_t, z_t, nb, n0_1, t, w, lm, q);
  }
}

// ---------------------------------------------------------------------------
// gmax_kernel: zm[b][n][128] = max_k z[b][idx[n,k]][128].  (unchanged)
// ---------------------------------------------------------------------------
__global__ __launch_bounds__(256) void gmax_kernel(
    const unsigned short* __restrict__ z_t, const int* __restrict__ e0,
    unsigned short* __restrict__ zm)
{
  const int bid = blockIdx.x;
  const int b   = bid & 7;
  const int n0  = (bid >> 3) * 64;
  const int t   = threadIdx.x;
  const int nl  = t >> 2, c = t & 3;
  const int gn  = n0 + nl;
  if (gn >= NODES) return;          // no barrier in this kernel: safe

  const int* ip = e0 + ((size_t)b * NODES + gn) * KNB;
  int4 iv0 = *(const int4*)(ip);
  int4 iv1 = *(const int4*)(ip + 4);
  int4 iv2 = *(const int4*)(ip + 8);
  int4 iv3 = *(const int4*)(ip + 12);
  int idx[16] = {iv0.x, iv0.y, iv0.z, iv0.w,
                 iv1.x, iv1.y, iv1.z, iv1.w,
                 iv2.x, iv2.y, iv2.z, iv2.w,
                 iv3.x, iv3.y, iv3.z, iv3.w};

  const char* Z = (const char*)(z_t + (size_t)b * NODES * CH) + c * 16;
  uint4 m[4];
#pragma unroll
  for (int cg = 0; cg < 4; ++cg) m[cg] = make_uint4(0u, 0u, 0u, 0u);

#pragma unroll
  for (int k = 0; k < KNB; ++k) {
    const char* p = Z + (size_t)idx[k] * (CH * 2);
#pragma unroll
    for (int cg = 0; cg < 4; ++cg)
      m[cg] = pkmax4(m[cg], *(const uint4*)(p + cg * 64));
  }

  char* O = (char*)(zm + ((size_t)b * NODES + gn) * CH) + c * 16;
#pragma unroll
  for (int cg = 0; cg < 4; ++cg)
    *(uint4*)(O + cg * 64) = m[cg];
}

// ---------------------------------------------------------------------------
// out_gemm v6: v5 pipeline + T4 counted vmcnt. Per iteration the order is
// stage(next)[8 DMA, oldest] -> epi(prev)[64 stores, newer] -> mfma(cur) ->
// vmcnt(56): waits >=16 oldest ops (the 8 DMAs + a few stores) while the
// bulk of the store burst drains under the NEXT tile's MFMA. Prologue
// boundaries (no stores outstanding) must stay vmcnt(0).
// ---------------------------------------------------------------------------
__device__ __forceinline__ void og_stage(
    unsigned short* buf, const unsigned short* __restrict__ h_t,
    const unsigned short* __restrict__ zm, size_t nb, int n0, int w, int lane)
{
#pragma unroll
  for (int rep = 0; rep < 8; ++rep) {
    const int row0 = w * 2 + rep * 8;            // wave-uniform row pair
    const int nl = row0 + (lane >> 5);
    const int l  = (lane & 31) ^ (nl & 7);       // pre-swizzled source chunk
    int gn = n0 + nl; if (gn > NODES - 1) gn = NODES - 1;   // clamp, masked later
    const unsigned short* src = (l < 16)
        ? h_t + (nb + (size_t)gn) * CH + l * 8
        : zm  + (nb + (size_t)gn) * CH + (l - 16) * 8;
    gload_lds16(src, (char*)buf + row0 * 512);
  }
  __builtin_amdgcn_sched_barrier(0);             // pin DMA issue (oldest VMEM)
}

__device__ __forceinline__ void og_mfma(
    f32x4 (&acc)[4][4], const unsigned short* buf,
    const uint4 (&af)[8][4], int lm, int q)
{
  const char* catB = (const char*)buf;
#pragma unroll
  for (int dt = 0; dt < 4; ++dt)
#pragma unroll
    for (int nt = 0; nt < 4; ++nt) acc[dt][nt] = (f32x4){0.f, 0.f, 0.f, 0.f};
#pragma unroll
  for (int kt = 0; kt < 8; ++kt)
#pragma unroll
    for (int nt = 0; nt < 4; ++nt) {
      int nl = nt * 16 + lm;
      int chunk = kt * 4 + q;
      int phys = nl * 512 + ((chunk ^ (nl & 7)) << 4);
      bf16x8 bb = asbf8(*(const uint4*)(catB + phys));
#pragma unroll
      for (int dt = 0; dt < 4; ++dt)
        acc[dt][nt] = __builtin_amdgcn_mfma_f32_16x16x32_bf16(
            asbf8(af[kt][dt]), bb, acc[dt][nt], 0, 0, 0);
    }
}

__device__ __forceinline__ void og_epi(
    const f32x4 (&acc)[4][4], const float* __restrict__ b2,
    float* __restrict__ out, int b, int n0, int w, int lm, int q)
{
  const int d0 = w * 64;
#pragma unroll
  for (int dt = 0; dt < 4; ++dt) {
    int dbase = d0 + dt * 16 + q * 4;
    float4 bi = *(const float4*)(b2 + dbase);
    float bv[4] = {bi.x, bi.y, bi.z, bi.w};
#pragma unroll
    for (int nt = 0; nt < 4; ++nt) {
      int gn = n0 + nt * 16 + lm;
      if (gn < NODES) {
        float* op = out + ((size_t)(b * CO + dbase) * NODES) + gn;
#pragma unroll
        for (int r = 0; r < 4; ++r)
          op[(size_t)r * NODES] = fmaxf(acc[dt][nt][r] + bv[r], 0.f);
      }
    }
  }
}

__global__ __launch_bounds__(256) void out_gemm(
    const unsigned short* __restrict__ h_t, const unsigned short* __restrict__ zm,
    const unsigned short* __restrict__ W2b, const float* __restrict__ b2,
    float* __restrict__ out)
{
  const int bid = blockIdx.x;
  const int b   = bid & 7;
  const int g   = bid >> 3;                // 0..63
  const int t   = threadIdx.x;
  const int lane = t & 63, w = t >> 6;
  const int lm = lane & 15, q = lane >> 4;
  const size_t nb = (size_t)b * NODES;

  __shared__ __align__(16) unsigned short bufA[64 * 256];   // 32 KB
  __shared__ __align__(16) unsigned short bufB[64 * 256];   // 32 KB

  // W2 A-fragments, tile-invariant: af[kt][dt]
  const int d0 = w * 64;
  uint4 af[8][4];
#pragma unroll
  for (int kt = 0; kt < 8; ++kt)
#pragma unroll
    for (int dt = 0; dt < 4; ++dt)
      af[kt][dt] = *(const uint4*)(W2b + (d0 + dt*16 + lm) * CO + kt*32 + q*8);

  const int n0_0 = g * 64;
  const int n0_1 = (g + 64) * 64;
  const int n0_2 = (g + 128) * 64;
  const bool has2 = (g + 128) < 157;

  f32x4 acc[4][4];

  // prologue: stage tile0 (must be vmcnt(0): nothing newer outstanding)
  og_stage(bufA, h_t, zm, nb, n0_0, w, lane);
  asm volatile("s_waitcnt vmcnt(0) lgkmcnt(0)" ::: "memory");
  __builtin_amdgcn_sched_barrier(0);
  __builtin_amdgcn_s_barrier();

  // iter 0: stage t1, compute t0 (no stores yet -> vmcnt(0))
  og_stage(bufB, h_t, zm, nb, n0_1, w, lane);
  og_mfma(acc, bufA, af, lm, q);
  asm volatile("s_waitcnt vmcnt(0) lgkmcnt(0)" ::: "memory");
  __builtin_amdgcn_sched_barrier(0);
  __builtin_amdgcn_s_barrier();

  if (has2) {
    // iter 1: stage t2 (oldest) -> epi t0 (newer) -> mfma t1 -> counted wait
    og_stage(bufA, h_t, zm, nb, n0_2, w, lane);
    og_epi(acc, b2, out, b, n0_0, w, lm, q);
    og_mfma(acc, bufB, af, lm, q);
    asm volatile("s_waitcnt vmcnt(56) lgkmcnt(0)" ::: "memory");  // DMAs only
    __builtin_amdgcn_sched_barrier(0);
    __builtin_amdgcn_s_barrier();
    // iter 2: t1 stores drain under t2 MFMA
    og_epi(acc, b2, out, b, n0_1, w, lm, q);
    og_mfma(acc, bufA, af, lm, q);
    og_epi(acc, b2, out, b, n0_2, w, lm, q);
  } else {
    // t0 stores drain under t1 MFMA naturally (no wait between)
    og_epi(acc, b2, out, b, n0_0, w, lm, q);
    og_mfma(acc, bufB, af, lm, q);
    og_epi(acc, b2, out, b, n0_1, w, lm, q);
  }
}

// ---------------------------------------------------------------------------
extern "C" void kernel_launch(void* const* d_in, const int* in_sizes, int n_in,
                              void* d_out, int out_size, void* d_ws, size_t ws_size,
                              hipStream_t stream) {
  const float* x  = (const float*)d_in[0];
  const int*   ei = (const int*)d_in[1];   // (2,B,N,K); first half = targets
  const float* W1 = (const float*)d_in[2];
  const float* b1 = (const float*)d_in[3];
  const float* Wp = (const float*)d_in[4];
  const float* bp = (const float*)d_in[5];
  const float* W2 = (const float*)d_in[6];
  const float* b2 = (const float*)d_in[7];
  float* out = (float*)d_out;

  unsigned short* ws  = (unsigned short*)d_ws;
  unsigned short* h_t = ws;                                   // [B][N][128] bf16
  unsigned short* z_t = h_t + (size_t)BATCH * NODES * CH;     // [B][N][128] bf16
  unsigned short* W1b = z_t + (size_t)BATCH * NODES * CH;
  unsigned short* Wpb = W1b + CH * CH;
  unsigned short* W2b = Wpb + CH * CH;
  unsigned short* zm  = W2b + CO * 2 * CH;                    // [B][N][128] bf16
  unsigned short* x_t = zm  + (size_t)BATCH * NODES * CH;     // [B][N][128] bf16

  prep<<<96, 256, 0, stream>>>(W1, Wp, W2, W1b, Wpb, W2b);

  const int NT = (NODES + 63) / 64;         // 157 tiles of 64 nodes
  prep_x<<<dim3(NT, BATCH), 256, 0, stream>>>(x, x_t);
  fused_hz<<<512, 256, 0, stream>>>(W1b, b1, Wpb, bp, x_t, h_t, z_t);
  gmax_kernel<<<BATCH * NT, 256, 0, stream>>>(z_t, ei, zm);
  out_gemm<<<512, 256, 0, stream>>>(h_t, zm, W2b, b2, out);
}

// Round 9
// 194.920 us; speedup vs baseline: 1.0059x; 1.0059x over previous
//
#include <hip/hip_runtime.h>

#define NODES 10000
#define BATCH 8
#define CH    128
#define KNB   16
#define CO    256

typedef __bf16 bf16x8 __attribute__((ext_vector_type(8)));
typedef float  f32x4  __attribute__((ext_vector_type(4)));

__device__ __forceinline__ unsigned short f2bf(float f) {
  unsigned u = __float_as_uint(f);
  u = (u + 0x7FFFu + ((u >> 16) & 1u)) >> 16;   // RNE
  return (unsigned short)u;
}

// max of packed non-negative bf16 == packed u16 max (relu guarantees >=0)
__device__ __forceinline__ unsigned pkmax(unsigned a, unsigned b) {
  unsigned d;
  asm("v_pk_max_u16 %0, %1, %2" : "=v"(d) : "v"(a), "v"(b));
  return d;
}
__device__ __forceinline__ uint4 pkmax4(uint4 a, uint4 b) {
  a.x = pkmax(a.x, b.x); a.y = pkmax(a.y, b.y);
  a.z = pkmax(a.z, b.z); a.w = pkmax(a.w, b.w);
  return a;
}
__device__ __forceinline__ bf16x8 asbf8(uint4 u) {
  union { uint4 u; bf16x8 b; } c; c.u = u; return c.b;
}

// async global->LDS DMA, 16B per lane; LDS dst = base + lane*16 (linear)
__device__ __forceinline__ void gload_lds16(const void* g, void* l) {
  __builtin_amdgcn_global_load_lds(
      (const __attribute__((address_space(1))) unsigned int*)g,
      (__attribute__((address_space(3))) unsigned int*)l, 16, 0, 0);
}

// LDS-only barrier: waits LDS ops, NOT outstanding global stores / LDS-DMA.
__device__ __forceinline__ void lds_barrier() {
  asm volatile("s_waitcnt lgkmcnt(0)" ::: "memory");
  __builtin_amdgcn_sched_barrier(0);
  __builtin_amdgcn_s_barrier();
}

// ---------------------------------------------------------------------------
// fp32 -> bf16 weight conversion (row-major [d][k] kept)
// ---------------------------------------------------------------------------
__global__ __launch_bounds__(256) void prep(
    const float* __restrict__ W1, const float* __restrict__ Wp,
    const float* __restrict__ W2,
    unsigned short* __restrict__ W1b, unsigned short* __restrict__ Wpb,
    unsigned short* __restrict__ W2b)
{
  int i = blockIdx.x * 256 + threadIdx.x;   // float4 index, 24576 total
  const float* src; unsigned short* dst; int off;
  if (i < 4096)      { src = W1; dst = W1b; off = i; }
  else if (i < 8192) { src = Wp; dst = Wpb; off = i - 4096; }
  else               { src = W2; dst = W2b; off = i - 8192; }
  float4 v = ((const float4*)src)[off];
  ushort4 o;
  o.x = f2bf(v.x); o.y = f2bf(v.y); o.z = f2bf(v.z); o.w = f2bf(v.w);
  ((ushort4*)dst)[off] = o;
}

// ---------------------------------------------------------------------------
// fused_hz v5: prep_x fused back in via T14 reg-staging.
// Stage(next) = {load 8x dwordx4 of fp32 x into regs (issued BEFORE
// compute(cur), latency hides under the two GEMMs)} ... {f2bf + swizzled
// ds_write after compute}. x_t round-trip (41 MB) and the prep_x launch are
// eliminated. Double-buffer: buf written at iter k was last read at iter
// k-1, separated by __syncthreads (R8 showed counted-vmcnt is not binding
// here, so plain barriers for simplicity).
// ---------------------------------------------------------------------------
__device__ __forceinline__ void hz_load_x(
    f32x4 (&xa)[4][2], const float* __restrict__ X, int n0, int t)
{
#pragma unroll
  for (int rep = 0; rep < 4; ++rep) {
    int flat = t + rep * 256;
    int c2 = flat >> 4, n4 = flat & 15;
    int c  = c2 * 2;
    int gn = n0 + n4 * 4;
    f32x4 a0 = (f32x4){0.f,0.f,0.f,0.f}, a1 = a0;
    if (gn < NODES) {
      a0 = *(const f32x4*)(X + (size_t)c * NODES + gn);
      a1 = *(const f32x4*)(X + (size_t)(c + 1) * NODES + gn);
    }
    xa[rep][0] = a0; xa[rep][1] = a1;
  }
}

__device__ __forceinline__ void hz_write_buf(
    const f32x4 (&xa)[4][2], unsigned short* buf, int t)
{
  char* BtB = (char*)buf;
#pragma unroll
  for (int rep = 0; rep < 4; ++rep) {
    int flat = t + rep * 256;
    int c2 = flat >> 4, n4 = flat & 15;
#pragma unroll
    for (int i = 0; i < 4; ++i) {
      int nn = n4 * 4 + i;
      unsigned pk = (unsigned)f2bf(xa[rep][0][i])
                  | ((unsigned)f2bf(xa[rep][1][i]) << 16);
      int phys = nn * 256 + (((c2 >> 2) ^ (nn & 7)) << 4) + ((c2 & 3) << 2);
      *(unsigned*)(BtB + phys) = pk;
    }
  }
}

__device__ __forceinline__ void hz_compute(
    const unsigned short* buf, unsigned short* Ht, unsigned short* Zt,
    const uint4 (&af)[4][4], const uint4 (&af2)[4][4],
    const float* __restrict__ b1, const float* __restrict__ bp,
    unsigned short* __restrict__ h_t, unsigned short* __restrict__ z_t,
    size_t nb, int n0, int t, int w, int lm, int q)
{
  const char* BtB = (const char*)buf;
  char* HtB = (char*)Ht;
  char* ZtB = (char*)Zt;
  const int d0  = (w & 1) * 64;
  const int nbw = (w >> 1) * 32;

  // ---- phase 1 MFMA: h-tile
  f32x4 acc[4][2];
#pragma unroll
  for (int dt = 0; dt < 4; ++dt)
#pragma unroll
    for (int nt = 0; nt < 2; ++nt) acc[dt][nt] = (f32x4){0.f,0.f,0.f,0.f};

#pragma unroll
  for (int kt = 0; kt < 4; ++kt)
#pragma unroll
    for (int nt = 0; nt < 2; ++nt) {
      int nl = nbw + nt * 16 + lm;
      int chunk = kt * 4 + q;
      int phys = nl * 256 + ((chunk ^ (nl & 7)) << 4);
      bf16x8 bb = asbf8(*(const uint4*)(BtB + phys));
#pragma unroll
      for (int dt = 0; dt < 4; ++dt)
        acc[dt][nt] = __builtin_amdgcn_mfma_f32_16x16x32_bf16(
            asbf8(af[dt][kt]), bb, acc[dt][nt], 0, 0, 0);
    }

  // ---- epilogue 1: bias+relu+bf16 -> Ht (B-frag layout)
#pragma unroll
  for (int dt = 0; dt < 4; ++dt) {
    int dbase = d0 + dt * 16 + q * 4;
    float4 bi = *(const float4*)(b1 + dbase);
    float bv[4] = {bi.x, bi.y, bi.z, bi.w};
#pragma unroll
    for (int nt = 0; nt < 2; ++nt) {
      int nl = nbw + nt * 16 + lm;
      ushort4 o;
      o.x = f2bf(fmaxf(acc[dt][nt][0] + bv[0], 0.f));
      o.y = f2bf(fmaxf(acc[dt][nt][1] + bv[1], 0.f));
      o.z = f2bf(fmaxf(acc[dt][nt][2] + bv[2], 0.f));
      o.w = f2bf(fmaxf(acc[dt][nt][3] + bv[3], 0.f));
      int chunk = dbase >> 3;
      int phys  = nl * 256 + ((chunk ^ (nl & 7)) << 4) + ((q & 1) << 3);
      *(ushort4*)(HtB + phys) = o;
    }
  }

  lds_barrier();   // Ht complete (LDS-only: stores stay in flight)

  // ---- coalesced h_t store (fire-and-forget; drains under MFMA2)
  {
    int nl = t >> 2;
    int gn = n0 + nl;
#pragma unroll
    for (int rep = 0; rep < 4; ++rep) {
      int g = (t & 3) + rep * 4;
      int phys = nl * 256 + ((g ^ (nl & 7)) << 4);
      uint4 v = *(const uint4*)(HtB + phys);
      if (gn < NODES)
        *(uint4*)((char*)h_t + (nb + (size_t)gn) * 256 + g * 16) = v;
    }
  }

  // ---- phase 2 MFMA: z-tile from Ht
#pragma unroll
  for (int dt = 0; dt < 4; ++dt)
#pragma unroll
    for (int nt = 0; nt < 2; ++nt) acc[dt][nt] = (f32x4){0.f,0.f,0.f,0.f};

#pragma unroll
  for (int kt = 0; kt < 4; ++kt)
#pragma unroll
    for (int nt = 0; nt < 2; ++nt) {
      int nl = nbw + nt * 16 + lm;
      int chunk = kt * 4 + q;
      int phys = nl * 256 + ((chunk ^ (nl & 7)) << 4);
      bf16x8 bb = asbf8(*(const uint4*)(HtB + phys));
#pragma unroll
      for (int dt = 0; dt < 4; ++dt)
        acc[dt][nt] = __builtin_amdgcn_mfma_f32_16x16x32_bf16(
            asbf8(af2[dt][kt]), bb, acc[dt][nt], 0, 0, 0);
    }

  // ---- epilogue 2: z -> Zt (B-frag layout)
#pragma unroll
  for (int dt = 0; dt < 4; ++dt) {
    int dbase = d0 + dt * 16 + q * 4;
    float4 bi = *(const float4*)(bp + dbase);
    float bv[4] = {bi.x, bi.y, bi.z, bi.w};
#pragma unroll
    for (int nt = 0; nt < 2; ++nt) {
      int nl = nbw + nt * 16 + lm;
      ushort4 o;
      o.x = f2bf(fmaxf(acc[dt][nt][0] + bv[0], 0.f));
      o.y = f2bf(fmaxf(acc[dt][nt][1] + bv[1], 0.f));
      o.z = f2bf(fmaxf(acc[dt][nt][2] + bv[2], 0.f));
      o.w = f2bf(fmaxf(acc[dt][nt][3] + bv[3], 0.f));
      int chunk = dbase >> 3;
      int phys  = nl * 256 + ((chunk ^ (nl & 7)) << 4) + ((q & 1) << 3);
      *(ushort4*)(ZtB + phys) = o;
    }
  }

  lds_barrier();   // Zt complete (LDS-only)

  // ---- coalesced z_t store (fire-and-forget)
  {
    int nl = t >> 2;
    int gn = n0 + nl;
#pragma unroll
    for (int rep = 0; rep < 4; ++rep) {
      int g = (t & 3) + rep * 4;
      int phys = nl * 256 + ((g ^ (nl & 7)) << 4);
      uint4 v = *(const uint4*)(ZtB + phys);
      if (gn < NODES)
        *(uint4*)((char*)z_t + (nb + (size_t)gn) * 256 + g * 16) = v;
    }
  }
}

__global__ __launch_bounds__(256) void fused_hz(
    const unsigned short* __restrict__ W1b, const float* __restrict__ b1,
    const unsigned short* __restrict__ Wpb, const float* __restrict__ bp,
    const float* __restrict__ x,
    unsigned short* __restrict__ h_t, unsigned short* __restrict__ z_t)
{
  const int bid = blockIdx.x;
  const int b   = bid & 7;
  const int g   = bid >> 3;                // 0..63
  const int t   = threadIdx.x;
  const int lane = t & 63, w = t >> 6;
  const int lm = lane & 15, q = lane >> 4;
  const size_t nb = (size_t)b * NODES;
  const float* X = x + (size_t)b * CH * NODES;

  __shared__ __align__(16) unsigned short bufA[64 * 128];   // 16 KB
  __shared__ __align__(16) unsigned short bufB[64 * 128];   // 16 KB
  __shared__ __align__(16) unsigned short Ht[64 * 128];     // 16 KB
  __shared__ __align__(16) unsigned short Zt[64 * 128];     // 16 KB

  const int d0 = (w & 1) * 64;

  // W1 + Wp A-fragments, tile-invariant (preload once)
  uint4 af[4][4], af2[4][4];
#pragma unroll
  for (int dt = 0; dt < 4; ++dt)
#pragma unroll
    for (int kt = 0; kt < 4; ++kt) {
      af[dt][kt]  = *(const uint4*)(W1b + (d0 + dt*16 + lm) * CH + kt*32 + q*8);
      af2[dt][kt] = *(const uint4*)(Wpb + (d0 + dt*16 + lm) * CH + kt*32 + q*8);
    }

  const int n0_0 = g * 64;
  const int n0_1 = (g + 64) * 64;
  const int n0_2 = (g + 128) * 64;
  const bool has2 = (g + 128) < 157;

  f32x4 xa[4][2];

  // prologue: stage tile0 (not overlapped — once per block)
  hz_load_x(xa, X, n0_0, t);
  hz_write_buf(xa, bufA, t);
  __syncthreads();

  // iter 0: issue tile1 x-loads EARLY, compute tile0 (hides load latency),
  // then convert+write bufB
  hz_load_x(xa, X, n0_1, t);
  hz_compute(bufA, Ht, Zt, af, af2, b1, bp, h_t, z_t, nb, n0_0, t, w, lm, q);
  hz_write_buf(xa, bufB, t);
  __syncthreads();

  if (has2) {
    hz_load_x(xa, X, n0_2, t);
    hz_compute(bufB, Ht, Zt, af, af2, b1, bp, h_t, z_t, nb, n0_1, t, w, lm, q);
    hz_write_buf(xa, bufA, t);
    __syncthreads();
    hz_compute(bufA, Ht, Zt, af, af2, b1, bp, h_t, z_t, nb, n0_2, t, w, lm, q);
  } else {
    hz_compute(bufB, Ht, Zt, af, af2, b1, bp, h_t, z_t, nb, n0_1, t, w, lm, q);
  }
}

// ---------------------------------------------------------------------------
// gmax_kernel: zm[b][n][128] = max_k z[b][idx[n,k]][128].  (unchanged)
// ---------------------------------------------------------------------------
__global__ __launch_bounds__(256) void gmax_kernel(
    const unsigned short* __restrict__ z_t, const int* __restrict__ e0,
    unsigned short* __restrict__ zm)
{
  const int bid = blockIdx.x;
  const int b   = bid & 7;
  const int n0  = (bid >> 3) * 64;
  const int t   = threadIdx.x;
  const int nl  = t >> 2, c = t & 3;
  const int gn  = n0 + nl;
  if (gn >= NODES) return;          // no barrier in this kernel: safe

  const int* ip = e0 + ((size_t)b * NODES + gn) * KNB;
  int4 iv0 = *(const int4*)(ip);
  int4 iv1 = *(const int4*)(ip + 4);
  int4 iv2 = *(const int4*)(ip + 8);
  int4 iv3 = *(const int4*)(ip + 12);
  int idx[16] = {iv0.x, iv0.y, iv0.z, iv0.w,
                 iv1.x, iv1.y, iv1.z, iv1.w,
                 iv2.x, iv2.y, iv2.z, iv2.w,
                 iv3.x, iv3.y, iv3.z, iv3.w};

  const char* Z = (const char*)(z_t + (size_t)b * NODES * CH) + c * 16;
  uint4 m[4];
#pragma unroll
  for (int cg = 0; cg < 4; ++cg) m[cg] = make_uint4(0u, 0u, 0u, 0u);

#pragma unroll
  for (int k = 0; k < KNB; ++k) {
    const char* p = Z + (size_t)idx[k] * (CH * 2);
#pragma unroll
    for (int cg = 0; cg < 4; ++cg)
      m[cg] = pkmax4(m[cg], *(const uint4*)(p + cg * 64));
  }

  char* O = (char*)(zm + ((size_t)b * NODES + gn) * CH) + c * 16;
#pragma unroll
  for (int cg = 0; cg < 4; ++cg)
    *(uint4*)(O + cg * 64) = m[cg];
}

// ---------------------------------------------------------------------------
// out_gemm v6 (unchanged from R8; ~30 us).
// ---------------------------------------------------------------------------
__device__ __forceinline__ void og_stage(
    unsigned short* buf, const unsigned short* __restrict__ h_t,
    const unsigned short* __restrict__ zm, size_t nb, int n0, int w, int lane)
{
#pragma unroll
  for (int rep = 0; rep < 8; ++rep) {
    const int row0 = w * 2 + rep * 8;            // wave-uniform row pair
    const int nl = row0 + (lane >> 5);
    const int l  = (lane & 31) ^ (nl & 7);       // pre-swizzled source chunk
    int gn = n0 + nl; if (gn > NODES - 1) gn = NODES - 1;   // clamp, masked later
    const unsigned short* src = (l < 16)
        ? h_t + (nb + (size_t)gn) * CH + l * 8
        : zm  + (nb + (size_t)gn) * CH + (l - 16) * 8;
    gload_lds16(src, (char*)buf + row0 * 512);
  }
  __builtin_amdgcn_sched_barrier(0);             // pin DMA issue (oldest VMEM)
}

__device__ __forceinline__ void og_mfma(
    f32x4 (&acc)[4][4], const unsigned short* buf,
    const uint4 (&af)[8][4], int lm, int q)
{
  const char* catB = (const char*)buf;
#pragma unroll
  for (int dt = 0; dt < 4; ++dt)
#pragma unroll
    for (int nt = 0; nt < 4; ++nt) acc[dt][nt] = (f32x4){0.f, 0.f, 0.f, 0.f};
#pragma unroll
  for (int kt = 0; kt < 8; ++kt)
#pragma unroll
    for (int nt = 0; nt < 4; ++nt) {
      int nl = nt * 16 + lm;
      int chunk = kt * 4 + q;
      int phys = nl * 512 + ((chunk ^ (nl & 7)) << 4);
      bf16x8 bb = asbf8(*(const uint4*)(catB + phys));
#pragma unroll
      for (int dt = 0; dt < 4; ++dt)
        acc[dt][nt] = __builtin_amdgcn_mfma_f32_16x16x32_bf16(
            asbf8(af[kt][dt]), bb, acc[dt][nt], 0, 0, 0);
    }
}

__device__ __forceinline__ void og_epi(
    const f32x4 (&acc)[4][4], const float* __restrict__ b2,
    float* __restrict__ out, int b, int n0, int w, int lm, int q)
{
  const int d0 = w * 64;
#pragma unroll
  for (int dt = 0; dt < 4; ++dt) {
    int dbase = d0 + dt * 16 + q * 4;
    float4 bi = *(const float4*)(b2 + dbase);
    float bv[4] = {bi.x, bi.y, bi.z, bi.w};
#pragma unroll
    for (int nt = 0; nt < 4; ++nt) {
      int gn = n0 + nt * 16 + lm;
      if (gn < NODES) {
        float* op = out + ((size_t)(b * CO + dbase) * NODES) + gn;
#pragma unroll
        for (int r = 0; r < 4; ++r)
          op[(size_t)r * NODES] = fmaxf(acc[dt][nt][r] + bv[r], 0.f);
      }
    }
  }
}

__global__ __launch_bounds__(256) void out_gemm(
    const unsigned short* __restrict__ h_t, const unsigned short* __restrict__ zm,
    const unsigned short* __restrict__ W2b, const float* __restrict__ b2,
    float* __restrict__ out)
{
  const int bid = blockIdx.x;
  const int b   = bid & 7;
  const int g   = bid >> 3;                // 0..63
  const int t   = threadIdx.x;
  const int lane = t & 63, w = t >> 6;
  const int lm = lane & 15, q = lane >> 4;
  const size_t nb = (size_t)b * NODES;

  __shared__ __align__(16) unsigned short bufA[64 * 256];   // 32 KB
  __shared__ __align__(16) unsigned short bufB[64 * 256];   // 32 KB

  // W2 A-fragments, tile-invariant: af[kt][dt]
  const int d0 = w * 64;
  uint4 af[8][4];
#pragma unroll
  for (int kt = 0; kt < 8; ++kt)
#pragma unroll
    for (int dt = 0; dt < 4; ++dt)
      af[kt][dt] = *(const uint4*)(W2b + (d0 + dt*16 + lm) * CO + kt*32 + q*8);

  const int n0_0 = g * 64;
  const int n0_1 = (g + 64) * 64;
  const int n0_2 = (g + 128) * 64;
  const bool has2 = (g + 128) < 157;

  f32x4 acc[4][4];

  // prologue: stage tile0 (must be vmcnt(0): nothing newer outstanding)
  og_stage(bufA, h_t, zm, nb, n0_0, w, lane);
  asm volatile("s_waitcnt vmcnt(0) lgkmcnt(0)" ::: "memory");
  __builtin_amdgcn_sched_barrier(0);
  __builtin_amdgcn_s_barrier();

  // iter 0: stage t1, compute t0 (no stores yet -> vmcnt(0))
  og_stage(bufB, h_t, zm, nb, n0_1, w, lane);
  og_mfma(acc, bufA, af, lm, q);
  asm volatile("s_waitcnt vmcnt(0) lgkmcnt(0)" ::: "memory");
  __builtin_amdgcn_sched_barrier(0);
  __builtin_amdgcn_s_barrier();

  if (has2) {
    // iter 1: stage t2 (oldest) -> epi t0 (newer) -> mfma t1 -> counted wait
    og_stage(bufA, h_t, zm, nb, n0_2, w, lane);
    og_epi(acc, b2, out, b, n0_0, w, lm, q);
    og_mfma(acc, bufB, af, lm, q);
    asm volatile("s_waitcnt vmcnt(56) lgkmcnt(0)" ::: "memory");  // DMAs only
    __builtin_amdgcn_sched_barrier(0);
    __builtin_amdgcn_s_barrier();
    // iter 2: t1 stores drain under t2 MFMA
    og_epi(acc, b2, out, b, n0_1, w, lm, q);
    og_mfma(acc, bufA, af, lm, q);
    og_epi(acc, b2, out, b, n0_2, w, lm, q);
  } else {
    // t0 stores drain under t1 MFMA naturally (no wait between)
    og_epi(acc, b2, out, b, n0_0, w, lm, q);
    og_mfma(acc, bufB, af, lm, q);
    og_epi(acc, b2, out, b, n0_1, w, lm, q);
  }
}

// ---------------------------------------------------------------------------
extern "C" void kernel_launch(void* const* d_in, const int* in_sizes, int n_in,
                              void* d_out, int out_size, void* d_ws, size_t ws_size,
                              hipStream_t stream) {
  const float* x  = (const float*)d_in[0];
  const int*   ei = (const int*)d_in[1];   // (2,B,N,K); first half = targets
  const float* W1 = (const float*)d_in[2];
  const float* b1 = (const float*)d_in[3];
  const float* Wp = (const float*)d_in[4];
  const float* bp = (const float*)d_in[5];
  const float* W2 = (const float*)d_in[6];
  const float* b2 = (const float*)d_in[7];
  float* out = (float*)d_out;

  unsigned short* ws  = (unsigned short*)d_ws;
  unsigned short* h_t = ws;                                   // [B][N][128] bf16
  unsigned short* z_t = h_t + (size_t)BATCH * NODES * CH;     // [B][N][128] bf16
  unsigned short* W1b = z_t + (size_t)BATCH * NODES * CH;
  unsigned short* Wpb = W1b + CH * CH;
  unsigned short* W2b = Wpb + CH * CH;
  unsigned short* zm  = W2b + CO * 2 * CH;                    // [B][N][128] bf16

  prep<<<96, 256, 0, stream>>>(W1, Wp, W2, W1b, Wpb, W2b);

  const int NT = (NODES + 63) / 64;         // 157 tiles of 64 nodes
  fused_hz<<<512, 256, 0, stream>>>(W1b, b1, Wpb, bp, x, h_t, z_t);
  gmax_kernel<<<BATCH * NT, 256, 0, stream>>>(z_t, ei, zm);
  out_gemm<<<512, 256, 0, stream>>>(h_t, zm, W2b, b2, out);
}